// Round 9
// baseline (274.059 us; speedup 1.0000x reference)
//
#include <hip/hip_runtime.h>
#include <hip/hip_bf16.h>
#include <math.h>

#define B_ 4
#define T_ 2048
#define D_ 1024
#define H_ 16
#define HD_ 64

typedef _Float16 f16x8 __attribute__((ext_vector_type(8)));
typedef _Float16 f16x4 __attribute__((ext_vector_type(4)));
typedef __fp16 h16x2 __attribute__((ext_vector_type(2)));   // cvt_pkrtz native type
typedef float f32x4 __attribute__((ext_vector_type(4)));

// async global->LDS, 16 B per lane, dest = wave-uniform base + lane*16
__device__ __forceinline__ void gload_lds16(const _Float16* g, _Float16* l) {
    __builtin_amdgcn_global_load_lds(
        (const __attribute__((address_space(1))) void*)g,
        (__attribute__((address_space(3))) void*)l,
        16, 0, 0);
}

// ---------------------------------------------------------------------------
// Fused input + 4-weight fp32 -> fp16 cast, one launch.
// ---------------------------------------------------------------------------
__global__ __launch_bounds__(256) void castall(const float* __restrict__ x,
                                               const float* __restrict__ wq,
                                               const float* __restrict__ wk,
                                               const float* __restrict__ wv,
                                               const float* __restrict__ wo,
                                               _Float16* __restrict__ xh,
                                               _Float16* __restrict__ wqh,
                                               _Float16* __restrict__ wkh,
                                               _Float16* __restrict__ wvh,
                                               _Float16* __restrict__ woh) {
    const int gi = blockIdx.x * 256 + threadIdx.x;
    const float* in;
    _Float16* out;
    int off;
    if (gi < (1 << 21)) {
        in = x; out = xh; off = gi;
    } else {
        const int j = gi - (1 << 21);
        const int w = j >> 18;
        off = j & ((1 << 18) - 1);
        in  = (w == 0) ? wq : (w == 1 ? wk : (w == 2 ? wv : wo));
        out = (w == 0) ? wqh : (w == 1 ? wkh : (w == 2 ? wvh : woh));
    }
    const float4 v = ((const float4*)in)[off];
    f16x4 h = {(_Float16)v.x, (_Float16)v.y, (_Float16)v.z, (_Float16)v.w};
    ((f16x4*)out)[off] = h;
}

// ---------------------------------------------------------------------------
// Fused QKV GEMM + rmsnorm/rotary epilogue.
// ROUND 9: BK 32 -> 64 in the same 2-barrier m97 skeleton — halves the
// per-K-iter vmcnt(0)+lgkm drain count (32 -> 16 iters), the documented
// ~20% stall of this structure.  [128][64] f16 rows are a 16-way bank
// conflict, so BK=64 carries the XOR swizzle verified in round 1 (passed,
// conflicts=0): pre-swizzled global source chunk ((lane&7)^(row&7)) into
// linear LDS dest + read at physical chunk (logical ^ (row&7)).
// LDS 32 KB (m132's BK=128 failure was the 64 KB occupancy cliff — avoided).
// z=0: rms+rotary+0.125*log2e -> qh ; z=1: rms+rotary -> kh ;
// z=2: plain -> vt transposed [b][h][d][T]
// ---------------------------------------------------------------------------
__global__ __launch_bounds__(256) void gemm_qkv(const _Float16* __restrict__ A,
                                                const _Float16* __restrict__ Wq,
                                                const _Float16* __restrict__ Wk,
                                                const _Float16* __restrict__ Wv,
                                                _Float16* __restrict__ qh,
                                                _Float16* __restrict__ kh,
                                                _Float16* __restrict__ vt) {
    constexpr int K = D_;
    const int z = blockIdx.z;
    const _Float16* W = (z == 0) ? Wq : (z == 1 ? Wk : Wv);
    __shared__ _Float16 As[128 * 64];
    __shared__ _Float16 Bs[128 * 64];
    const int tid = threadIdx.x;
    const int lane = tid & 63, w = tid >> 6;
    const int col = lane & 15, quad = lane >> 4;
    const int wm = w >> 1, wn = w & 1;
    const int row0 = blockIdx.y * 128, col0 = blockIdx.x * 128;

    // staging: 8 rows per wave-call; source chunk pre-swizzled by row-in-8
    const int sr8 = lane >> 3;
    const int sch = (((lane & 7) ^ sr8) << 3);
    // fragment reads: logical chunk c lives at physical c ^ (row&7); row%16==col
    const int swz = col & 7;
    const int c0s = ((quad ^ swz) << 3);
    const int c1s = (((quad | 4) ^ swz) << 3);

    f32x4 acc[4][4];
#pragma unroll
    for (int i = 0; i < 4; ++i)
#pragma unroll
        for (int j = 0; j < 4; ++j) acc[i][j] = (f32x4){0.f, 0.f, 0.f, 0.f};

    for (int kt = 0; kt < K / 64; ++kt) {
        const int k0 = kt * 64;
#pragma unroll
        for (int i = 0; i < 4; ++i) {
            const int rb = w * 32 + i * 8;
            gload_lds16(A + (size_t)(row0 + rb + sr8) * K + k0 + sch, As + rb * 64);
            gload_lds16(W + (size_t)(col0 + rb + sr8) * K + k0 + sch, Bs + rb * 64);
        }
        __syncthreads();
        f16x8 af[4][2], bf[4][2];
#pragma unroll
        for (int i = 0; i < 4; ++i) {
            const int ra = (wm * 64 + i * 16 + col) * 64;
            af[i][0] = *(const f16x8*)&As[ra + c0s];
            af[i][1] = *(const f16x8*)&As[ra + c1s];
            const int rb2 = (wn * 64 + i * 16 + col) * 64;
            bf[i][0] = *(const f16x8*)&Bs[rb2 + c0s];
            bf[i][1] = *(const f16x8*)&Bs[rb2 + c1s];
        }
#pragma unroll
        for (int mi = 0; mi < 4; ++mi)
#pragma unroll
            for (int ni = 0; ni < 4; ++ni) {
                acc[mi][ni] = __builtin_amdgcn_mfma_f32_16x16x32_f16(af[mi][0], bf[ni][0],
                                                                     acc[mi][ni], 0, 0, 0);
                acc[mi][ni] = __builtin_amdgcn_mfma_f32_16x16x32_f16(af[mi][1], bf[ni][1],
                                                                     acc[mi][ni], 0, 0, 0);
            }
        __syncthreads();
    }

    if (z < 2) {
        _Float16* C = (z == 0) ? qh : kh;
        const float qscale = (z == 0) ? 0.18033688011112042f : 1.0f;  // 0.125*log2(e)
        const float fr = exp2f(-10.0f * (float)col * (1.0f / 15.0f));
#pragma unroll
        for (int mi = 0; mi < 4; ++mi) {
            float ssq[4];
#pragma unroll
            for (int r = 0; r < 4; ++r) {
                float t = 0.f;
#pragma unroll
                for (int ni = 0; ni < 4; ++ni) t += acc[mi][ni][r] * acc[mi][ni][r];
                ssq[r] = t;
            }
#pragma unroll
            for (int st = 1; st < 16; st <<= 1)
#pragma unroll
                for (int r = 0; r < 4; ++r) ssq[r] += __shfl_xor(ssq[r], st, 64);
            const int rowb = row0 + wm * 64 + mi * 16 + quad * 4;
#pragma unroll
            for (int r = 0; r < 4; ++r) {
                const float scl = rsqrtf(ssq[r] * (1.0f / 64.0f) + 1e-6f) * qscale;
                const int t = (rowb + r) & (T_ - 1);
                float s, c;
                sincosf((float)t * fr, &s, &c);
                const float x0 = acc[mi][0][r] * scl;
                const float x1 = acc[mi][1][r] * scl;
                const float x2 = acc[mi][2][r] * scl;
                const float x3 = acc[mi][3][r] * scl;
                const float y0 = fmaf(x0, c, x2 * s);
                const float y2 = fmaf(x2, c, -x0 * s);
                const size_t base = (size_t)(rowb + r) * D_ + col0 + wn * 64 + col;
                C[base + 0]  = (_Float16)y0;
                C[base + 16] = (_Float16)x1;
                C[base + 32] = (_Float16)y2;
                C[base + 48] = (_Float16)x3;
            }
        }
    } else {
        const int hh = blockIdx.x * 2 + wn;
#pragma unroll
        for (int mi = 0; mi < 4; ++mi) {
            const int row = row0 + wm * 64 + mi * 16 + quad * 4;
            const int bb = row >> 11;
            const int t0m = row & (T_ - 1);
#pragma unroll
            for (int ni = 0; ni < 4; ++ni) {
                const int d = ni * 16 + col;
                f16x4 pk = {(_Float16)acc[mi][ni][0], (_Float16)acc[mi][ni][1],
                            (_Float16)acc[mi][ni][2], (_Float16)acc[mi][ni][3]};
                *(f16x4*)&vt[((size_t)(bb * H_ + hh) * HD_ + d) * T_ + t0m] = pk;
            }
        }
    }
}

// ---------------------------------------------------------------------------
// WO GEMM: out[M,N] = A[M,K] @ W[N,K]^T, fp16 in, fp32 out.
// ROUND 9: same BK=64 + swizzle transformation as gemm_qkv.
// ---------------------------------------------------------------------------
__global__ __launch_bounds__(256) void gemm_wo(const _Float16* __restrict__ A,
                                               const _Float16* __restrict__ W,
                                               float* __restrict__ C) {
    constexpr int K = D_, N = D_;
    __shared__ _Float16 As[128 * 64];
    __shared__ _Float16 Bs[128 * 64];
    const int tid = threadIdx.x;
    const int lane = tid & 63, w = tid >> 6;
    const int col = lane & 15, quad = lane >> 4;
    const int wm = w >> 1, wn = w & 1;
    const int row0 = blockIdx.y * 128, col0 = blockIdx.x * 128;

    const int sr8 = lane >> 3;
    const int sch = (((lane & 7) ^ sr8) << 3);
    const int swz = col & 7;
    const int c0s = ((quad ^ swz) << 3);
    const int c1s = (((quad | 4) ^ swz) << 3);

    f32x4 acc[4][4];
#pragma unroll
    for (int i = 0; i < 4; ++i)
#pragma unroll
        for (int j = 0; j < 4; ++j) acc[i][j] = (f32x4){0.f, 0.f, 0.f, 0.f};

    for (int kt = 0; kt < K / 64; ++kt) {
        const int k0 = kt * 64;
#pragma unroll
        for (int i = 0; i < 4; ++i) {
            const int rb = w * 32 + i * 8;
            gload_lds16(A + (size_t)(row0 + rb + sr8) * K + k0 + sch, As + rb * 64);
            gload_lds16(W + (size_t)(col0 + rb + sr8) * K + k0 + sch, Bs + rb * 64);
        }
        __syncthreads();
        f16x8 af[4][2], bf[4][2];
#pragma unroll
        for (int i = 0; i < 4; ++i) {
            const int ra = (wm * 64 + i * 16 + col) * 64;
            af[i][0] = *(const f16x8*)&As[ra + c0s];
            af[i][1] = *(const f16x8*)&As[ra + c1s];
            const int rb2 = (wn * 64 + i * 16 + col) * 64;
            bf[i][0] = *(const f16x8*)&Bs[rb2 + c0s];
            bf[i][1] = *(const f16x8*)&Bs[rb2 + c1s];
        }
#pragma unroll
        for (int mi = 0; mi < 4; ++mi)
#pragma unroll
            for (int ni = 0; ni < 4; ++ni) {
                acc[mi][ni] = __builtin_amdgcn_mfma_f32_16x16x32_f16(af[mi][0], bf[ni][0],
                                                                     acc[mi][ni], 0, 0, 0);
                acc[mi][ni] = __builtin_amdgcn_mfma_f32_16x16x32_f16(af[mi][1], bf[ni][1],
                                                                     acc[mi][ni], 0, 0, 0);
            }
        __syncthreads();
    }
#pragma unroll
    for (int mi = 0; mi < 4; ++mi)
#pragma unroll
        for (int ni = 0; ni < 4; ++ni)
#pragma unroll
            for (int r = 0; r < 4; ++r)
                C[(size_t)(row0 + wm * 64 + mi * 16 + quad * 4 + r) * N +
                  col0 + wn * 64 + ni * 16 + col] = acc[mi][ni][r];
}

// ---------------------------------------------------------------------------
// MFMA flash attention (fp16 in/out). 512 thr = 8 waves, 128 q per block,
// wave w owns q rows [q0+16w, q0+16w+16). K-tiles of 64 keys.
// ROUND 8 version retained (verified win: native exp2, cvt_pkrtz packing,
// fully-masked-tile skip; dbuf + single vmcnt(0)+s_barrier per tile).
// ---------------------------------------------------------------------------
#define LDP 88

__global__ __launch_bounds__(512) void flash_mfma(const _Float16* __restrict__ qh,
                                                  const _Float16* __restrict__ kh,
                                                  const _Float16* __restrict__ vt,
                                                  _Float16* __restrict__ o) {
    __shared__ _Float16 Kl[2][64 * 64];
    __shared__ _Float16 Vl[2][64 * 64];
    __shared__ _Float16 Pl[8][16 * LDP];
    const int tid = threadIdx.x;
    const int lane = tid & 63, w = tid >> 6;           // w in [0,8)
    const int col = lane & 15, quad = lane >> 4;
    const int bh = blockIdx.x, b = bh >> 4, h = bh & 15;
    const int srow = lane >> 3;                        // row-in-8 for staging
    const int schunk = (lane & 7) ^ srow;              // global-side swizzle
    const int sw = col & 7;                            // read-side swizzle key
    const int rstg = w * 8 + srow;                     // staged row (0..63)

    const _Float16* kbase = kh + ((size_t)b * T_ * H_ + (size_t)h) * HD_;
    const _Float16* vbase = vt + ((size_t)(b * H_ + h)) * (size_t)HD_ * T_;

    for (int phase = 0; phase < 2; ++phase) {
        const int qt = (phase == 0) ? (int)blockIdx.y : (15 - (int)blockIdx.y);
        const int q0 = qt * 128;

        // Q as B-operand: lane holds Q[q=q0+16w+col][d = quad*8+j (+32)]
        const int tq = q0 + w * 16 + col;
        const _Float16* qp = qh + ((size_t)(b * T_ + tq) * H_ + h) * HD_ + quad * 8;
        const f16x8 qB0 = *(const f16x8*)(qp);
        const f16x8 qB1 = *(const f16x8*)(qp + 32);

        f32x4 oa[4];
#pragma unroll
        for (int i = 0; i < 4; ++i) oa[i] = (f32x4){0.f, 0.f, 0.f, 0.f};
        float l_ = 0.f;  // per-lane partial denom for q = col

        const int nkt = 2 * qt + 2;
        const int qmax = q0 + w * 16 + 15;   // this wave's largest q row

        // ---- prologue: stage tile 0 -> buf 0, full drain ----
        gload_lds16(kbase + (size_t)(0 + rstg) * H_ * HD_ + schunk * 8,
                    &Kl[0][(w * 8) * 64]);
        gload_lds16(vbase + (size_t)rstg * T_ + 0 + schunk * 8,
                    &Vl[0][(w * 8) * 64]);
        __builtin_amdgcn_sched_barrier(0);
        asm volatile("s_waitcnt vmcnt(0)" ::: "memory");
        __builtin_amdgcn_sched_barrier(0);
        __builtin_amdgcn_s_barrier();

        for (int kt = 0; kt < nkt; ++kt) {
            const int k0 = kt * 64;
            const int cur = kt & 1;

            // ---- issue next tile's stage early (hides under compute) ----
            if (kt + 1 < nkt) {
                gload_lds16(kbase + (size_t)(k0 + 64 + rstg) * H_ * HD_ + schunk * 8,
                            &Kl[cur ^ 1][(w * 8) * 64]);
                gload_lds16(vbase + (size_t)rstg * T_ + k0 + 64 + schunk * 8,
                            &Vl[cur ^ 1][(w * 8) * 64]);
            }

            // ---- fully-masked tile for this wave: skip compute entirely ----
            if (k0 <= qmax) {
                // ---- S^T[key][q]: A = K rows, B = Q (in regs) ----
                f32x4 s[4];
                __builtin_amdgcn_s_setprio(1);
#pragma unroll
                for (int tn = 0; tn < 4; ++tn) {
                    const _Float16* kp = &Kl[cur][(tn * 16 + col) * 64];
                    const f16x8 kA0 = *(const f16x8*)(kp + ((quad ^ sw) << 3));
                    const f16x8 kA1 = *(const f16x8*)(kp + (((quad | 4) ^ sw) << 3));
                    f32x4 a = (f32x4){0.f, 0.f, 0.f, 0.f};
                    a = __builtin_amdgcn_mfma_f32_16x16x32_f16(kA0, qB0, a, 0, 0, 0);
                    a = __builtin_amdgcn_mfma_f32_16x16x32_f16(kA1, qB1, a, 0, 0, 0);
                    s[tn] = a;
                }
                __builtin_amdgcn_s_setprio(0);

                // ---- causal mask: any key in tile beyond this wave's q rows ----
                if (k0 + 63 > q0 + w * 16) {
                    const int qq = q0 + w * 16 + col;
#pragma unroll
                    for (int tn = 0; tn < 4; ++tn)
#pragma unroll
                        for (int r = 0; r < 4; ++r) {
                            const int key = k0 + tn * 16 + quad * 4 + r;
                            if (key > qq) s[tn][r] = -1e30f;
                        }
                }

                // ---- p = exp2(s) [native], l accumulate, packed P store ----
#pragma unroll
                for (int tn = 0; tn < 4; ++tn) {
                    float p0 = __builtin_amdgcn_exp2f(s[tn][0]);
                    float p1 = __builtin_amdgcn_exp2f(s[tn][1]);
                    float p2 = __builtin_amdgcn_exp2f(s[tn][2]);
                    float p3 = __builtin_amdgcn_exp2f(s[tn][3]);
                    l_ += (p0 + p1) + (p2 + p3);
                    union { f16x4 v; h16x2 h[2]; } u;
                    u.h[0] = __builtin_amdgcn_cvt_pkrtz(p0, p1);
                    u.h[1] = __builtin_amdgcn_cvt_pkrtz(p2, p3);
                    *(f16x4*)&Pl[w][col * LDP + tn * 16 + quad * 4] = u.v;
                }

                // ---- O[q][d] += P @ V (Pl[w] wave-private, no barrier) ----
                const f16x8 pA0 = *(const f16x8*)&Pl[w][col * LDP + quad * 8];
                const f16x8 pA1 = *(const f16x8*)&Pl[w][col * LDP + quad * 8 + 32];
                __builtin_amdgcn_s_setprio(1);
#pragma unroll
                for (int tn = 0; tn < 4; ++tn) {
                    const _Float16* vp = &Vl[cur][(tn * 16 + col) * 64];
                    const f16x8 vB0 = *(const f16x8*)(vp + ((quad ^ sw) << 3));
                    const f16x8 vB1 = *(const f16x8*)(vp + (((quad | 4) ^ sw) << 3));
                    oa[tn] = __builtin_amdgcn_mfma_f32_16x16x32_f16(pA0, vB0, oa[tn], 0, 0, 0);
                    oa[tn] = __builtin_amdgcn_mfma_f32_16x16x32_f16(pA1, vB1, oa[tn], 0, 0, 0);
                }
                __builtin_amdgcn_s_setprio(0);
            }

            // ---- single per-tile sync: next tile landed + all waves done ----
            __builtin_amdgcn_sched_barrier(0);
            asm volatile("s_waitcnt vmcnt(0)" ::: "memory");
            __builtin_amdgcn_sched_barrier(0);
            __builtin_amdgcn_s_barrier();
        }

        // ---- finish l (sum quads), redistribute to O rows, write ----
        l_ += __shfl_xor(l_, 16, 64);
        l_ += __shfl_xor(l_, 32, 64);
        const float linv = 1.0f / l_;
        float inv[4];
#pragma unroll
        for (int r = 0; r < 4; ++r) inv[r] = __shfl(linv, quad * 4 + r, 64);
#pragma unroll
        for (int tn = 0; tn < 4; ++tn)
#pragma unroll
            for (int r = 0; r < 4; ++r)
                o[((size_t)(b * T_ + q0 + w * 16 + quad * 4 + r) * H_ + h) * HD_ + tn * 16 + col] =
                    (_Float16)(oa[tn][r] * inv[r]);
    }
}

// ---------------------------------------------------------------------------
extern "C" void kernel_launch(void* const* d_in, const int* in_sizes, int n_in,
                              void* d_out, int out_size, void* d_ws, size_t ws_size,
                              hipStream_t stream) {
    const float* x  = (const float*)d_in[0];
    const float* wq = (const float*)d_in[1];
    const float* wk = (const float*)d_in[2];
    const float* wv = (const float*)d_in[3];
    const float* wo = (const float*)d_in[4];
    float* out = (float*)d_out;

    const size_t NE = (size_t)B_ * T_ * D_;   // 8,388,608
    const size_t WE = (size_t)D_ * D_;        // 1,048,576
    _Float16* xh  = (_Float16*)d_ws;
    _Float16* qh  = xh + NE;
    _Float16* kh  = qh + NE;
    _Float16* vth = kh + NE;
    _Float16* oh  = vth + NE;
    _Float16* wqh = oh + NE;
    _Float16* wkh = wqh + WE;
    _Float16* wvh = wkh + WE;
    _Float16* woh = wvh + WE;

    // fused casts: 2^21 (x) + 4 * 2^18 (weights) float4s = 12288 blocks
    castall<<<12288, 256, 0, stream>>>(x, wq, wk, wv, wo,
                                       xh, wqh, wkh, wvh, woh);

    gemm_qkv<<<dim3(D_ / 128, (B_ * T_) / 128, 3), 256, 0, stream>>>(
        xh, wqh, wkh, wvh, qh, kh, vth);

    flash_mfma<<<dim3(B_ * H_, 8, 1), 512, 0, stream>>>(qh, kh, vth, oh);

    gemm_wo<<<dim3(D_ / 128, (B_ * T_) / 128, 1), 256, 0, stream>>>(oh, woh, out);
}

// Round 10
// 269.800 us; speedup vs baseline: 1.0158x; 1.0158x over previous
//
#include <hip/hip_runtime.h>
#include <hip/hip_bf16.h>
#include <math.h>

#define B_ 4
#define T_ 2048
#define D_ 1024
#define H_ 16
#define HD_ 64

typedef _Float16 f16x8 __attribute__((ext_vector_type(8)));
typedef _Float16 f16x4 __attribute__((ext_vector_type(4)));
typedef __fp16 h16x2 __attribute__((ext_vector_type(2)));   // cvt_pkrtz native type
typedef float f32x4 __attribute__((ext_vector_type(4)));

// async global->LDS, 16 B per lane, dest = wave-uniform base + lane*16
__device__ __forceinline__ void gload_lds16(const _Float16* g, _Float16* l) {
    __builtin_amdgcn_global_load_lds(
        (const __attribute__((address_space(1))) void*)g,
        (__attribute__((address_space(3))) void*)l,
        16, 0, 0);
}

// ---------------------------------------------------------------------------
// Fused input + 4-weight fp32 -> fp16 cast, one launch.
// ---------------------------------------------------------------------------
__global__ __launch_bounds__(256) void castall(const float* __restrict__ x,
                                               const float* __restrict__ wq,
                                               const float* __restrict__ wk,
                                               const float* __restrict__ wv,
                                               const float* __restrict__ wo,
                                               _Float16* __restrict__ xh,
                                               _Float16* __restrict__ wqh,
                                               _Float16* __restrict__ wkh,
                                               _Float16* __restrict__ wvh,
                                               _Float16* __restrict__ woh) {
    const int gi = blockIdx.x * 256 + threadIdx.x;
    const float* in;
    _Float16* out;
    int off;
    if (gi < (1 << 21)) {
        in = x; out = xh; off = gi;
    } else {
        const int j = gi - (1 << 21);
        const int w = j >> 18;
        off = j & ((1 << 18) - 1);
        in  = (w == 0) ? wq : (w == 1 ? wk : (w == 2 ? wv : wo));
        out = (w == 0) ? wqh : (w == 1 ? wkh : (w == 2 ? wvh : woh));
    }
    const float4 v = ((const float4*)in)[off];
    f16x4 h = {(_Float16)v.x, (_Float16)v.y, (_Float16)v.z, (_Float16)v.w};
    ((f16x4*)out)[off] = h;
}

// ---------------------------------------------------------------------------
// Fused QKV GEMM + rmsnorm/rotary epilogue (m97 BK=32 structure — REVERTED
// from BK=64: round 9 showed occupancy 29->19%, VALUBusy 21->39, FETCH
// 135->200MB; the 2.3-blocks/CU implicit overlap of BK=32 beats every
// explicit scheme tried (8-phase r1-2, XCD swizzle r6, BK=64 r9)).
// ROUND 10: epilogue sincosf -> native v_sin/v_cos (revolutions input,
// rev = t*fr/2pi <= ~326, fract range-reduction; err ~1e-4 rad << fp16).
// z=0: rms+rotary+0.125*log2e -> qh ; z=1: rms+rotary -> kh ;
// z=2: plain -> vt transposed [b][h][d][T]
// ---------------------------------------------------------------------------
__global__ __launch_bounds__(256) void gemm_qkv(const _Float16* __restrict__ A,
                                                const _Float16* __restrict__ Wq,
                                                const _Float16* __restrict__ Wk,
                                                const _Float16* __restrict__ Wv,
                                                _Float16* __restrict__ qh,
                                                _Float16* __restrict__ kh,
                                                _Float16* __restrict__ vt) {
    constexpr int K = D_;
    const int z = blockIdx.z;
    const _Float16* W = (z == 0) ? Wq : (z == 1 ? Wk : Wv);
    __shared__ _Float16 As[128 * 32];
    __shared__ _Float16 Bs[128 * 32];
    const int tid = threadIdx.x;
    const int lane = tid & 63, w = tid >> 6;
    const int col = lane & 15, quad = lane >> 4;
    const int wm = w >> 1, wn = w & 1;
    const int row0 = blockIdx.y * 128, col0 = blockIdx.x * 128;
    const int sr = lane >> 2, sc = (lane & 3) * 8;

    f32x4 acc[4][4];
#pragma unroll
    for (int i = 0; i < 4; ++i)
#pragma unroll
        for (int j = 0; j < 4; ++j) acc[i][j] = (f32x4){0.f, 0.f, 0.f, 0.f};

    for (int kt = 0; kt < K / 32; ++kt) {
        const int k0 = kt * 32;
#pragma unroll
        for (int it = 0; it < 2; ++it) {
            const int rb = it * 64 + w * 16;
            gload_lds16(A + (size_t)(row0 + rb + sr) * K + k0 + sc, As + rb * 32);
            gload_lds16(W + (size_t)(col0 + rb + sr) * K + k0 + sc, Bs + rb * 32);
        }
        __syncthreads();
        f16x8 af[4], bf[4];
#pragma unroll
        for (int i = 0; i < 4; ++i) {
            af[i] = *(const f16x8*)&As[(wm * 64 + i * 16 + col) * 32 + quad * 8];
            bf[i] = *(const f16x8*)&Bs[(wn * 64 + i * 16 + col) * 32 + quad * 8];
        }
#pragma unroll
        for (int mi = 0; mi < 4; ++mi)
#pragma unroll
            for (int ni = 0; ni < 4; ++ni)
                acc[mi][ni] = __builtin_amdgcn_mfma_f32_16x16x32_f16(af[mi], bf[ni],
                                                                     acc[mi][ni], 0, 0, 0);
        __syncthreads();
    }

    if (z < 2) {
        _Float16* C = (z == 0) ? qh : kh;
        const float qscale = (z == 0) ? 0.18033688011112042f : 1.0f;  // 0.125*log2(e)
        // rotary frequency in REVOLUTIONS per t: fr / (2*pi)
        const float fr2pi = exp2f(-10.0f * (float)col * (1.0f / 15.0f)) *
                            0.15915494309189535f;
#pragma unroll
        for (int mi = 0; mi < 4; ++mi) {
            float ssq[4];
#pragma unroll
            for (int r = 0; r < 4; ++r) {
                float t = 0.f;
#pragma unroll
                for (int ni = 0; ni < 4; ++ni) t += acc[mi][ni][r] * acc[mi][ni][r];
                ssq[r] = t;
            }
#pragma unroll
            for (int st = 1; st < 16; st <<= 1)
#pragma unroll
                for (int r = 0; r < 4; ++r) ssq[r] += __shfl_xor(ssq[r], st, 64);
            const int rowb = row0 + wm * 64 + mi * 16 + quad * 4;
#pragma unroll
            for (int r = 0; r < 4; ++r) {
                const float scl = rsqrtf(ssq[r] * (1.0f / 64.0f) + 1e-6f) * qscale;
                const int t = (rowb + r) & (T_ - 1);
                const float rev = (float)t * fr2pi;
                const float rf = rev - floorf(rev);            // v_fract range-reduce
                const float s = __builtin_amdgcn_sinf(rf);     // v_sin_f32 (revolutions)
                const float c = __builtin_amdgcn_cosf(rf);     // v_cos_f32
                const float x0 = acc[mi][0][r] * scl;
                const float x1 = acc[mi][1][r] * scl;
                const float x2 = acc[mi][2][r] * scl;
                const float x3 = acc[mi][3][r] * scl;
                const float y0 = fmaf(x0, c, x2 * s);
                const float y2 = fmaf(x2, c, -x0 * s);
                const size_t base = (size_t)(rowb + r) * D_ + col0 + wn * 64 + col;
                C[base + 0]  = (_Float16)y0;
                C[base + 16] = (_Float16)x1;
                C[base + 32] = (_Float16)y2;
                C[base + 48] = (_Float16)x3;
            }
        }
    } else {
        const int hh = blockIdx.x * 2 + wn;
#pragma unroll
        for (int mi = 0; mi < 4; ++mi) {
            const int row = row0 + wm * 64 + mi * 16 + quad * 4;
            const int bb = row >> 11;
            const int t0m = row & (T_ - 1);
#pragma unroll
            for (int ni = 0; ni < 4; ++ni) {
                const int d = ni * 16 + col;
                f16x4 pk = {(_Float16)acc[mi][ni][0], (_Float16)acc[mi][ni][1],
                            (_Float16)acc[mi][ni][2], (_Float16)acc[mi][ni][3]};
                *(f16x4*)&vt[((size_t)(bb * H_ + hh) * HD_ + d) * T_ + t0m] = pk;
            }
        }
    }
}

// ---------------------------------------------------------------------------
// WO GEMM: out[M,N] = A[M,K] @ W[N,K]^T, fp16 in, fp32 out. m97 BK=32
// structure (reverted from BK=64, same reasoning as gemm_qkv).
// ---------------------------------------------------------------------------
__global__ __launch_bounds__(256) void gemm_wo(const _Float16* __restrict__ A,
                                               const _Float16* __restrict__ W,
                                               float* __restrict__ C) {
    constexpr int K = D_, N = D_;
    __shared__ _Float16 As[128 * 32];
    __shared__ _Float16 Bs[128 * 32];
    const int tid = threadIdx.x;
    const int lane = tid & 63, w = tid >> 6;
    const int col = lane & 15, quad = lane >> 4;
    const int wm = w >> 1, wn = w & 1;
    const int row0 = blockIdx.y * 128, col0 = blockIdx.x * 128;
    const int sr = lane >> 2, sc = (lane & 3) * 8;

    f32x4 acc[4][4];
#pragma unroll
    for (int i = 0; i < 4; ++i)
#pragma unroll
        for (int j = 0; j < 4; ++j) acc[i][j] = (f32x4){0.f, 0.f, 0.f, 0.f};

    for (int kt = 0; kt < K / 32; ++kt) {
        const int k0 = kt * 32;
#pragma unroll
        for (int it = 0; it < 2; ++it) {
            const int rb = it * 64 + w * 16;
            gload_lds16(A + (size_t)(row0 + rb + sr) * K + k0 + sc, As + rb * 32);
            gload_lds16(W + (size_t)(col0 + rb + sr) * K + k0 + sc, Bs + rb * 32);
        }
        __syncthreads();
        f16x8 af[4], bf[4];
#pragma unroll
        for (int i = 0; i < 4; ++i) {
            af[i] = *(const f16x8*)&As[(wm * 64 + i * 16 + col) * 32 + quad * 8];
            bf[i] = *(const f16x8*)&Bs[(wn * 64 + i * 16 + col) * 32 + quad * 8];
        }
#pragma unroll
        for (int mi = 0; mi < 4; ++mi)
#pragma unroll
            for (int ni = 0; ni < 4; ++ni)
                acc[mi][ni] = __builtin_amdgcn_mfma_f32_16x16x32_f16(af[mi], bf[ni],
                                                                     acc[mi][ni], 0, 0, 0);
        __syncthreads();
    }
#pragma unroll
    for (int mi = 0; mi < 4; ++mi)
#pragma unroll
        for (int ni = 0; ni < 4; ++ni)
#pragma unroll
            for (int r = 0; r < 4; ++r)
                C[(size_t)(row0 + wm * 64 + mi * 16 + quad * 4 + r) * N +
                  col0 + wn * 64 + ni * 16 + col] = acc[mi][ni][r];
}

// ---------------------------------------------------------------------------
// MFMA flash attention (fp16 in/out). 512 thr = 8 waves, 128 q per block,
// wave w owns q rows [q0+16w, q0+16w+16). K-tiles of 64 keys.
// ROUND 8 version retained (verified win: native exp2, cvt_pkrtz packing,
// fully-masked-tile skip; dbuf + single vmcnt(0)+s_barrier per tile).
// ---------------------------------------------------------------------------
#define LDP 88

__global__ __launch_bounds__(512) void flash_mfma(const _Float16* __restrict__ qh,
                                                  const _Float16* __restrict__ kh,
                                                  const _Float16* __restrict__ vt,
                                                  _Float16* __restrict__ o) {
    __shared__ _Float16 Kl[2][64 * 64];
    __shared__ _Float16 Vl[2][64 * 64];
    __shared__ _Float16 Pl[8][16 * LDP];
    const int tid = threadIdx.x;
    const int lane = tid & 63, w = tid >> 6;           // w in [0,8)
    const int col = lane & 15, quad = lane >> 4;
    const int bh = blockIdx.x, b = bh >> 4, h = bh & 15;
    const int srow = lane >> 3;                        // row-in-8 for staging
    const int schunk = (lane & 7) ^ srow;              // global-side swizzle
    const int sw = col & 7;                            // read-side swizzle key
    const int rstg = w * 8 + srow;                     // staged row (0..63)

    const _Float16* kbase = kh + ((size_t)b * T_ * H_ + (size_t)h) * HD_;
    const _Float16* vbase = vt + ((size_t)(b * H_ + h)) * (size_t)HD_ * T_;

    for (int phase = 0; phase < 2; ++phase) {
        const int qt = (phase == 0) ? (int)blockIdx.y : (15 - (int)blockIdx.y);
        const int q0 = qt * 128;

        // Q as B-operand: lane holds Q[q=q0+16w+col][d = quad*8+j (+32)]
        const int tq = q0 + w * 16 + col;
        const _Float16* qp = qh + ((size_t)(b * T_ + tq) * H_ + h) * HD_ + quad * 8;
        const f16x8 qB0 = *(const f16x8*)(qp);
        const f16x8 qB1 = *(const f16x8*)(qp + 32);

        f32x4 oa[4];
#pragma unroll
        for (int i = 0; i < 4; ++i) oa[i] = (f32x4){0.f, 0.f, 0.f, 0.f};
        float l_ = 0.f;  // per-lane partial denom for q = col

        const int nkt = 2 * qt + 2;
        const int qmax = q0 + w * 16 + 15;   // this wave's largest q row

        // ---- prologue: stage tile 0 -> buf 0, full drain ----
        gload_lds16(kbase + (size_t)(0 + rstg) * H_ * HD_ + schunk * 8,
                    &Kl[0][(w * 8) * 64]);
        gload_lds16(vbase + (size_t)rstg * T_ + 0 + schunk * 8,
                    &Vl[0][(w * 8) * 64]);
        __builtin_amdgcn_sched_barrier(0);
        asm volatile("s_waitcnt vmcnt(0)" ::: "memory");
        __builtin_amdgcn_sched_barrier(0);
        __builtin_amdgcn_s_barrier();

        for (int kt = 0; kt < nkt; ++kt) {
            const int k0 = kt * 64;
            const int cur = kt & 1;

            // ---- issue next tile's stage early (hides under compute) ----
            if (kt + 1 < nkt) {
                gload_lds16(kbase + (size_t)(k0 + 64 + rstg) * H_ * HD_ + schunk * 8,
                            &Kl[cur ^ 1][(w * 8) * 64]);
                gload_lds16(vbase + (size_t)rstg * T_ + k0 + 64 + schunk * 8,
                            &Vl[cur ^ 1][(w * 8) * 64]);
            }

            // ---- fully-masked tile for this wave: skip compute entirely ----
            if (k0 <= qmax) {
                // ---- S^T[key][q]: A = K rows, B = Q (in regs) ----
                f32x4 s[4];
                __builtin_amdgcn_s_setprio(1);
#pragma unroll
                for (int tn = 0; tn < 4; ++tn) {
                    const _Float16* kp = &Kl[cur][(tn * 16 + col) * 64];
                    const f16x8 kA0 = *(const f16x8*)(kp + ((quad ^ sw) << 3));
                    const f16x8 kA1 = *(const f16x8*)(kp + (((quad | 4) ^ sw) << 3));
                    f32x4 a = (f32x4){0.f, 0.f, 0.f, 0.f};
                    a = __builtin_amdgcn_mfma_f32_16x16x32_f16(kA0, qB0, a, 0, 0, 0);
                    a = __builtin_amdgcn_mfma_f32_16x16x32_f16(kA1, qB1, a, 0, 0, 0);
                    s[tn] = a;
                }
                __builtin_amdgcn_s_setprio(0);

                // ---- causal mask: any key in tile beyond this wave's q rows ----
                if (k0 + 63 > q0 + w * 16) {
                    const int qq = q0 + w * 16 + col;
#pragma unroll
                    for (int tn = 0; tn < 4; ++tn)
#pragma unroll
                        for (int r = 0; r < 4; ++r) {
                            const int key = k0 + tn * 16 + quad * 4 + r;
                            if (key > qq) s[tn][r] = -1e30f;
                        }
                }

                // ---- p = exp2(s) [native], l accumulate, packed P store ----
#pragma unroll
                for (int tn = 0; tn < 4; ++tn) {
                    float p0 = __builtin_amdgcn_exp2f(s[tn][0]);
                    float p1 = __builtin_amdgcn_exp2f(s[tn][1]);
                    float p2 = __builtin_amdgcn_exp2f(s[tn][2]);
                    float p3 = __builtin_amdgcn_exp2f(s[tn][3]);
                    l_ += (p0 + p1) + (p2 + p3);
                    union { f16x4 v; h16x2 h[2]; } u;
                    u.h[0] = __builtin_amdgcn_cvt_pkrtz(p0, p1);
                    u.h[1] = __builtin_amdgcn_cvt_pkrtz(p2, p3);
                    *(f16x4*)&Pl[w][col * LDP + tn * 16 + quad * 4] = u.v;
                }

                // ---- O[q][d] += P @ V (Pl[w] wave-private, no barrier) ----
                const f16x8 pA0 = *(const f16x8*)&Pl[w][col * LDP + quad * 8];
                const f16x8 pA1 = *(const f16x8*)&Pl[w][col * LDP + quad * 8 + 32];
                __builtin_amdgcn_s_setprio(1);
#pragma unroll
                for (int tn = 0; tn < 4; ++tn) {
                    const _Float16* vp = &Vl[cur][(tn * 16 + col) * 64];
                    const f16x8 vB0 = *(const f16x8*)(vp + ((quad ^ sw) << 3));
                    const f16x8 vB1 = *(const f16x8*)(vp + (((quad | 4) ^ sw) << 3));
                    oa[tn] = __builtin_amdgcn_mfma_f32_16x16x32_f16(pA0, vB0, oa[tn], 0, 0, 0);
                    oa[tn] = __builtin_amdgcn_mfma_f32_16x16x32_f16(pA1, vB1, oa[tn], 0, 0, 0);
                }
                __builtin_amdgcn_s_setprio(0);
            }

            // ---- single per-tile sync: next tile landed + all waves done ----
            __builtin_amdgcn_sched_barrier(0);
            asm volatile("s_waitcnt vmcnt(0)" ::: "memory");
            __builtin_amdgcn_sched_barrier(0);
            __builtin_amdgcn_s_barrier();
        }

        // ---- finish l (sum quads), redistribute to O rows, write ----
        l_ += __shfl_xor(l_, 16, 64);
        l_ += __shfl_xor(l_, 32, 64);
        const float linv = 1.0f / l_;
        float inv[4];
#pragma unroll
        for (int r = 0; r < 4; ++r) inv[r] = __shfl(linv, quad * 4 + r, 64);
#pragma unroll
        for (int tn = 0; tn < 4; ++tn)
#pragma unroll
            for (int r = 0; r < 4; ++r)
                o[((size_t)(b * T_ + q0 + w * 16 + quad * 4 + r) * H_ + h) * HD_ + tn * 16 + col] =
                    (_Float16)(oa[tn][r] * inv[r]);
    }
}

// ---------------------------------------------------------------------------
extern "C" void kernel_launch(void* const* d_in, const int* in_sizes, int n_in,
                              void* d_out, int out_size, void* d_ws, size_t ws_size,
                              hipStream_t stream) {
    const float* x  = (const float*)d_in[0];
    const float* wq = (const float*)d_in[1];
    const float* wk = (const float*)d_in[2];
    const float* wv = (const float*)d_in[3];
    const float* wo = (const float*)d_in[4];
    float* out = (float*)d_out;

    const size_t NE = (size_t)B_ * T_ * D_;   // 8,388,608
    const size_t WE = (size_t)D_ * D_;        // 1,048,576
    _Float16* xh  = (_Float16*)d_ws;
    _Float16* qh  = xh + NE;
    _Float16* kh  = qh + NE;
    _Float16* vth = kh + NE;
    _Float16* oh  = vth + NE;
    _Float16* wqh = oh + NE;
    _Float16* wkh = wqh + WE;
    _Float16* wvh = wkh + WE;
    _Float16* woh = wvh + WE;

    // fused casts: 2^21 (x) + 4 * 2^18 (weights) float4s = 12288 blocks
    castall<<<12288, 256, 0, stream>>>(x, wq, wk, wv, wo,
                                       xh, wqh, wkh, wvh, woh);

    gemm_qkv<<<dim3(D_ / 128, (B_ * T_) / 128, 3), 256, 0, stream>>>(
        xh, wqh, wkh, wvh, qh, kh, vth);

    flash_mfma<<<dim3(B_ * H_, 8, 1), 512, 0, stream>>>(qh, kh, vth, oh);

    gemm_wo<<<dim3(D_ / 128, (B_ * T_) / 128, 1), 256, 0, stream>>>(oh, woh, out);
}

// Round 11
// 261.376 us; speedup vs baseline: 1.0485x; 1.0322x over previous
//
#include <hip/hip_runtime.h>
#include <hip/hip_bf16.h>
#include <math.h>

#define B_ 4
#define T_ 2048
#define D_ 1024
#define H_ 16
#define HD_ 64

typedef _Float16 f16x8 __attribute__((ext_vector_type(8)));
typedef _Float16 f16x4 __attribute__((ext_vector_type(4)));
typedef __fp16 h16x2 __attribute__((ext_vector_type(2)));   // cvt_pkrtz native type
typedef float f32x4 __attribute__((ext_vector_type(4)));

// async global->LDS, 16 B per lane, dest = wave-uniform base + lane*16
__device__ __forceinline__ void gload_lds16(const _Float16* g, _Float16* l) {
    __builtin_amdgcn_global_load_lds(
        (const __attribute__((address_space(1))) void*)g,
        (__attribute__((address_space(3))) void*)l,
        16, 0, 0);
}

// ---------------------------------------------------------------------------
// Fused input + 4-weight fp32 -> fp16 cast, one launch.
// ---------------------------------------------------------------------------
__global__ __launch_bounds__(256) void castall(const float* __restrict__ x,
                                               const float* __restrict__ wq,
                                               const float* __restrict__ wk,
                                               const float* __restrict__ wv,
                                               const float* __restrict__ wo,
                                               _Float16* __restrict__ xh,
                                               _Float16* __restrict__ wqh,
                                               _Float16* __restrict__ wkh,
                                               _Float16* __restrict__ wvh,
                                               _Float16* __restrict__ woh) {
    const int gi = blockIdx.x * 256 + threadIdx.x;
    const float* in;
    _Float16* out;
    int off;
    if (gi < (1 << 21)) {
        in = x; out = xh; off = gi;
    } else {
        const int j = gi - (1 << 21);
        const int w = j >> 18;
        off = j & ((1 << 18) - 1);
        in  = (w == 0) ? wq : (w == 1 ? wk : (w == 2 ? wv : wo));
        out = (w == 0) ? wqh : (w == 1 ? wkh : (w == 2 ? wvh : woh));
    }
    const float4 v = ((const float4*)in)[off];
    f16x4 h = {(_Float16)v.x, (_Float16)v.y, (_Float16)v.z, (_Float16)v.w};
    ((f16x4*)out)[off] = h;
}

// ---------------------------------------------------------------------------
// Fused QKV GEMM + rmsnorm/rotary epilogue (m97 BK=32 structure — the
// empirical optimum for this K=1024 shape; 8-phase (r1-2), XCD swizzle (r6),
// BK=64 (r9), and native-sincos epilogue (r10: FETCH 135->200MB, occupancy
// 29->20%) all regressed vs this configuration).
// z=0: rms+rotary+0.125*log2e -> qh ; z=1: rms+rotary -> kh ;
// z=2: plain -> vt transposed [b][h][d][T]
// ---------------------------------------------------------------------------
__global__ __launch_bounds__(256) void gemm_qkv(const _Float16* __restrict__ A,
                                                const _Float16* __restrict__ Wq,
                                                const _Float16* __restrict__ Wk,
                                                const _Float16* __restrict__ Wv,
                                                _Float16* __restrict__ qh,
                                                _Float16* __restrict__ kh,
                                                _Float16* __restrict__ vt) {
    constexpr int K = D_;
    const int z = blockIdx.z;
    const _Float16* W = (z == 0) ? Wq : (z == 1 ? Wk : Wv);
    __shared__ _Float16 As[128 * 32];
    __shared__ _Float16 Bs[128 * 32];
    const int tid = threadIdx.x;
    const int lane = tid & 63, w = tid >> 6;
    const int col = lane & 15, quad = lane >> 4;
    const int wm = w >> 1, wn = w & 1;
    const int row0 = blockIdx.y * 128, col0 = blockIdx.x * 128;
    const int sr = lane >> 2, sc = (lane & 3) * 8;

    f32x4 acc[4][4];
#pragma unroll
    for (int i = 0; i < 4; ++i)
#pragma unroll
        for (int j = 0; j < 4; ++j) acc[i][j] = (f32x4){0.f, 0.f, 0.f, 0.f};

    for (int kt = 0; kt < K / 32; ++kt) {
        const int k0 = kt * 32;
#pragma unroll
        for (int it = 0; it < 2; ++it) {
            const int rb = it * 64 + w * 16;
            gload_lds16(A + (size_t)(row0 + rb + sr) * K + k0 + sc, As + rb * 32);
            gload_lds16(W + (size_t)(col0 + rb + sr) * K + k0 + sc, Bs + rb * 32);
        }
        __syncthreads();
        f16x8 af[4], bf[4];
#pragma unroll
        for (int i = 0; i < 4; ++i) {
            af[i] = *(const f16x8*)&As[(wm * 64 + i * 16 + col) * 32 + quad * 8];
            bf[i] = *(const f16x8*)&Bs[(wn * 64 + i * 16 + col) * 32 + quad * 8];
        }
#pragma unroll
        for (int mi = 0; mi < 4; ++mi)
#pragma unroll
            for (int ni = 0; ni < 4; ++ni)
                acc[mi][ni] = __builtin_amdgcn_mfma_f32_16x16x32_f16(af[mi], bf[ni],
                                                                     acc[mi][ni], 0, 0, 0);
        __syncthreads();
    }

    if (z < 2) {
        _Float16* C = (z == 0) ? qh : kh;
        const float qscale = (z == 0) ? 0.18033688011112042f : 1.0f;  // 0.125*log2(e)
        const float fr = exp2f(-10.0f * (float)col * (1.0f / 15.0f));
#pragma unroll
        for (int mi = 0; mi < 4; ++mi) {
            float ssq[4];
#pragma unroll
            for (int r = 0; r < 4; ++r) {
                float t = 0.f;
#pragma unroll
                for (int ni = 0; ni < 4; ++ni) t += acc[mi][ni][r] * acc[mi][ni][r];
                ssq[r] = t;
            }
#pragma unroll
            for (int st = 1; st < 16; st <<= 1)
#pragma unroll
                for (int r = 0; r < 4; ++r) ssq[r] += __shfl_xor(ssq[r], st, 64);
            const int rowb = row0 + wm * 64 + mi * 16 + quad * 4;
#pragma unroll
            for (int r = 0; r < 4; ++r) {
                const float scl = rsqrtf(ssq[r] * (1.0f / 64.0f) + 1e-6f) * qscale;
                const int t = (rowb + r) & (T_ - 1);
                float s, c;
                sincosf((float)t * fr, &s, &c);
                const float x0 = acc[mi][0][r] * scl;
                const float x1 = acc[mi][1][r] * scl;
                const float x2 = acc[mi][2][r] * scl;
                const float x3 = acc[mi][3][r] * scl;
                const float y0 = fmaf(x0, c, x2 * s);
                const float y2 = fmaf(x2, c, -x0 * s);
                const size_t base = (size_t)(rowb + r) * D_ + col0 + wn * 64 + col;
                C[base + 0]  = (_Float16)y0;
                C[base + 16] = (_Float16)x1;
                C[base + 32] = (_Float16)y2;
                C[base + 48] = (_Float16)x3;
            }
        }
    } else {
        const int hh = blockIdx.x * 2 + wn;
#pragma unroll
        for (int mi = 0; mi < 4; ++mi) {
            const int row = row0 + wm * 64 + mi * 16 + quad * 4;
            const int bb = row >> 11;
            const int t0m = row & (T_ - 1);
#pragma unroll
            for (int ni = 0; ni < 4; ++ni) {
                const int d = ni * 16 + col;
                f16x4 pk = {(_Float16)acc[mi][ni][0], (_Float16)acc[mi][ni][1],
                            (_Float16)acc[mi][ni][2], (_Float16)acc[mi][ni][3]};
                *(f16x4*)&vt[((size_t)(bb * H_ + hh) * HD_ + d) * T_ + t0m] = pk;
            }
        }
    }
}

// ---------------------------------------------------------------------------
// WO GEMM: out[M,N] = A[M,K] @ W[N,K]^T, fp16 in, fp32 out. m97 BK=32.
// ---------------------------------------------------------------------------
__global__ __launch_bounds__(256) void gemm_wo(const _Float16* __restrict__ A,
                                               const _Float16* __restrict__ W,
                                               float* __restrict__ C) {
    constexpr int K = D_, N = D_;
    __shared__ _Float16 As[128 * 32];
    __shared__ _Float16 Bs[128 * 32];
    const int tid = threadIdx.x;
    const int lane = tid & 63, w = tid >> 6;
    const int col = lane & 15, quad = lane >> 4;
    const int wm = w >> 1, wn = w & 1;
    const int row0 = blockIdx.y * 128, col0 = blockIdx.x * 128;
    const int sr = lane >> 2, sc = (lane & 3) * 8;

    f32x4 acc[4][4];
#pragma unroll
    for (int i = 0; i < 4; ++i)
#pragma unroll
        for (int j = 0; j < 4; ++j) acc[i][j] = (f32x4){0.f, 0.f, 0.f, 0.f};

    for (int kt = 0; kt < K / 32; ++kt) {
        const int k0 = kt * 32;
#pragma unroll
        for (int it = 0; it < 2; ++it) {
            const int rb = it * 64 + w * 16;
            gload_lds16(A + (size_t)(row0 + rb + sr) * K + k0 + sc, As + rb * 32);
            gload_lds16(W + (size_t)(col0 + rb + sr) * K + k0 + sc, Bs + rb * 32);
        }
        __syncthreads();
        f16x8 af[4], bf[4];
#pragma unroll
        for (int i = 0; i < 4; ++i) {
            af[i] = *(const f16x8*)&As[(wm * 64 + i * 16 + col) * 32 + quad * 8];
            bf[i] = *(const f16x8*)&Bs[(wn * 64 + i * 16 + col) * 32 + quad * 8];
        }
#pragma unroll
        for (int mi = 0; mi < 4; ++mi)
#pragma unroll
            for (int ni = 0; ni < 4; ++ni)
                acc[mi][ni] = __builtin_amdgcn_mfma_f32_16x16x32_f16(af[mi], bf[ni],
                                                                     acc[mi][ni], 0, 0, 0);
        __syncthreads();
    }
#pragma unroll
    for (int mi = 0; mi < 4; ++mi)
#pragma unroll
        for (int ni = 0; ni < 4; ++ni)
#pragma unroll
            for (int r = 0; r < 4; ++r)
                C[(size_t)(row0 + wm * 64 + mi * 16 + quad * 4 + r) * N +
                  col0 + wn * 64 + ni * 16 + col] = acc[mi][ni][r];
}

// ---------------------------------------------------------------------------
// MFMA flash attention (fp16 in/out). 512 thr = 8 waves, 128 q per block,
// wave w owns q rows [q0+16w, q0+16w+16). K-tiles of 64 keys.
// Round-8 verified version: native exp2, cvt_pkrtz packing, fully-masked-
// tile skip; dbuf + single vmcnt(0)+s_barrier per tile; setprio on MFMA.
// ---------------------------------------------------------------------------
#define LDP 88

__global__ __launch_bounds__(512) void flash_mfma(const _Float16* __restrict__ qh,
                                                  const _Float16* __restrict__ kh,
                                                  const _Float16* __restrict__ vt,
                                                  _Float16* __restrict__ o) {
    __shared__ _Float16 Kl[2][64 * 64];
    __shared__ _Float16 Vl[2][64 * 64];
    __shared__ _Float16 Pl[8][16 * LDP];
    const int tid = threadIdx.x;
    const int lane = tid & 63, w = tid >> 6;           // w in [0,8)
    const int col = lane & 15, quad = lane >> 4;
    const int bh = blockIdx.x, b = bh >> 4, h = bh & 15;
    const int srow = lane >> 3;                        // row-in-8 for staging
    const int schunk = (lane & 7) ^ srow;              // global-side swizzle
    const int sw = col & 7;                            // read-side swizzle key
    const int rstg = w * 8 + srow;                     // staged row (0..63)

    const _Float16* kbase = kh + ((size_t)b * T_ * H_ + (size_t)h) * HD_;
    const _Float16* vbase = vt + ((size_t)(b * H_ + h)) * (size_t)HD_ * T_;

    for (int phase = 0; phase < 2; ++phase) {
        const int qt = (phase == 0) ? (int)blockIdx.y : (15 - (int)blockIdx.y);
        const int q0 = qt * 128;

        // Q as B-operand: lane holds Q[q=q0+16w+col][d = quad*8+j (+32)]
        const int tq = q0 + w * 16 + col;
        const _Float16* qp = qh + ((size_t)(b * T_ + tq) * H_ + h) * HD_ + quad * 8;
        const f16x8 qB0 = *(const f16x8*)(qp);
        const f16x8 qB1 = *(const f16x8*)(qp + 32);

        f32x4 oa[4];
#pragma unroll
        for (int i = 0; i < 4; ++i) oa[i] = (f32x4){0.f, 0.f, 0.f, 0.f};
        float l_ = 0.f;  // per-lane partial denom for q = col

        const int nkt = 2 * qt + 2;
        const int qmax = q0 + w * 16 + 15;   // this wave's largest q row

        // ---- prologue: stage tile 0 -> buf 0, full drain ----
        gload_lds16(kbase + (size_t)(0 + rstg) * H_ * HD_ + schunk * 8,
                    &Kl[0][(w * 8) * 64]);
        gload_lds16(vbase + (size_t)rstg * T_ + 0 + schunk * 8,
                    &Vl[0][(w * 8) * 64]);
        __builtin_amdgcn_sched_barrier(0);
        asm volatile("s_waitcnt vmcnt(0)" ::: "memory");
        __builtin_amdgcn_sched_barrier(0);
        __builtin_amdgcn_s_barrier();

        for (int kt = 0; kt < nkt; ++kt) {
            const int k0 = kt * 64;
            const int cur = kt & 1;

            // ---- issue next tile's stage early (hides under compute) ----
            if (kt + 1 < nkt) {
                gload_lds16(kbase + (size_t)(k0 + 64 + rstg) * H_ * HD_ + schunk * 8,
                            &Kl[cur ^ 1][(w * 8) * 64]);
                gload_lds16(vbase + (size_t)rstg * T_ + k0 + 64 + schunk * 8,
                            &Vl[cur ^ 1][(w * 8) * 64]);
            }

            // ---- fully-masked tile for this wave: skip compute entirely ----
            if (k0 <= qmax) {
                // ---- S^T[key][q]: A = K rows, B = Q (in regs) ----
                f32x4 s[4];
                __builtin_amdgcn_s_setprio(1);
#pragma unroll
                for (int tn = 0; tn < 4; ++tn) {
                    const _Float16* kp = &Kl[cur][(tn * 16 + col) * 64];
                    const f16x8 kA0 = *(const f16x8*)(kp + ((quad ^ sw) << 3));
                    const f16x8 kA1 = *(const f16x8*)(kp + (((quad | 4) ^ sw) << 3));
                    f32x4 a = (f32x4){0.f, 0.f, 0.f, 0.f};
                    a = __builtin_amdgcn_mfma_f32_16x16x32_f16(kA0, qB0, a, 0, 0, 0);
                    a = __builtin_amdgcn_mfma_f32_16x16x32_f16(kA1, qB1, a, 0, 0, 0);
                    s[tn] = a;
                }
                __builtin_amdgcn_s_setprio(0);

                // ---- causal mask: any key in tile beyond this wave's q rows ----
                if (k0 + 63 > q0 + w * 16) {
                    const int qq = q0 + w * 16 + col;
#pragma unroll
                    for (int tn = 0; tn < 4; ++tn)
#pragma unroll
                        for (int r = 0; r < 4; ++r) {
                            const int key = k0 + tn * 16 + quad * 4 + r;
                            if (key > qq) s[tn][r] = -1e30f;
                        }
                }

                // ---- p = exp2(s) [native], l accumulate, packed P store ----
#pragma unroll
                for (int tn = 0; tn < 4; ++tn) {
                    float p0 = __builtin_amdgcn_exp2f(s[tn][0]);
                    float p1 = __builtin_amdgcn_exp2f(s[tn][1]);
                    float p2 = __builtin_amdgcn_exp2f(s[tn][2]);
                    float p3 = __builtin_amdgcn_exp2f(s[tn][3]);
                    l_ += (p0 + p1) + (p2 + p3);
                    union { f16x4 v; h16x2 h[2]; } u;
                    u.h[0] = __builtin_amdgcn_cvt_pkrtz(p0, p1);
                    u.h[1] = __builtin_amdgcn_cvt_pkrtz(p2, p3);
                    *(f16x4*)&Pl[w][col * LDP + tn * 16 + quad * 4] = u.v;
                }

                // ---- O[q][d] += P @ V (Pl[w] wave-private, no barrier) ----
                const f16x8 pA0 = *(const f16x8*)&Pl[w][col * LDP + quad * 8];
                const f16x8 pA1 = *(const f16x8*)&Pl[w][col * LDP + quad * 8 + 32];
                __builtin_amdgcn_s_setprio(1);
#pragma unroll
                for (int tn = 0; tn < 4; ++tn) {
                    const _Float16* vp = &Vl[cur][(tn * 16 + col) * 64];
                    const f16x8 vB0 = *(const f16x8*)(vp + ((quad ^ sw) << 3));
                    const f16x8 vB1 = *(const f16x8*)(vp + (((quad | 4) ^ sw) << 3));
                    oa[tn] = __builtin_amdgcn_mfma_f32_16x16x32_f16(pA0, vB0, oa[tn], 0, 0, 0);
                    oa[tn] = __builtin_amdgcn_mfma_f32_16x16x32_f16(pA1, vB1, oa[tn], 0, 0, 0);
                }
                __builtin_amdgcn_s_setprio(0);
            }

            // ---- single per-tile sync: next tile landed + all waves done ----
            __builtin_amdgcn_sched_barrier(0);
            asm volatile("s_waitcnt vmcnt(0)" ::: "memory");
            __builtin_amdgcn_sched_barrier(0);
            __builtin_amdgcn_s_barrier();
        }

        // ---- finish l (sum quads), redistribute to O rows, write ----
        l_ += __shfl_xor(l_, 16, 64);
        l_ += __shfl_xor(l_, 32, 64);
        const float linv = 1.0f / l_;
        float inv[4];
#pragma unroll
        for (int r = 0; r < 4; ++r) inv[r] = __shfl(linv, quad * 4 + r, 64);
#pragma unroll
        for (int tn = 0; tn < 4; ++tn)
#pragma unroll
            for (int r = 0; r < 4; ++r)
                o[((size_t)(b * T_ + q0 + w * 16 + quad * 4 + r) * H_ + h) * HD_ + tn * 16 + col] =
                    (_Float16)(oa[tn][r] * inv[r]);
    }
}

// ---------------------------------------------------------------------------
extern "C" void kernel_launch(void* const* d_in, const int* in_sizes, int n_in,
                              void* d_out, int out_size, void* d_ws, size_t ws_size,
                              hipStream_t stream) {
    const float* x  = (const float*)d_in[0];
    const float* wq = (const float*)d_in[1];
    const float* wk = (const float*)d_in[2];
    const float* wv = (const float*)d_in[3];
    const float* wo = (const float*)d_in[4];
    float* out = (float*)d_out;

    const size_t NE = (size_t)B_ * T_ * D_;   // 8,388,608
    const size_t WE = (size_t)D_ * D_;        // 1,048,576
    _Float16* xh  = (_Float16*)d_ws;
    _Float16* qh  = xh + NE;
    _Float16* kh  = qh + NE;
    _Float16* vth = kh + NE;
    _Float16* oh  = vth + NE;
    _Float16* wqh = oh + NE;
    _Float16* wkh = wqh + WE;
    _Float16* wvh = wkh + WE;
    _Float16* woh = wvh + WE;

    // fused casts: 2^21 (x) + 4 * 2^18 (weights) float4s = 12288 blocks
    castall<<<12288, 256, 0, stream>>>(x, wq, wk, wv, wo,
                                       xh, wqh, wkh, wvh, woh);

    gemm_qkv<<<dim3(D_ / 128, (B_ * T_) / 128, 3), 256, 0, stream>>>(
        xh, wqh, wkh, wvh, qh, kh, vth);

    flash_mfma<<<dim3(B_ * H_, 8, 1), 512, 0, stream>>>(qh, kh, vth, oh);

    gemm_wo<<<dim3(D_ / 128, (B_ * T_) / 128, 1), 256, 0, stream>>>(oh, woh, out);
}